// Round 7
// baseline (34590.540 us; speedup 1.0000x reference)
//
#include <hip/hip_runtime.h>
#include <cstdint>
#include <cstddef>

// FBRNN: T=16384, F=2048, H=16, A=64, L=6, G=3H=48.
// gi0 GEMM precomputed in permuted layout [t][k*4+gate].
// Scan: 1 block x 512 threads, zero barriers in the step loop; LDS flag sync.
// R7 role map (SIMD = wv%4; chain must not share a SIMD with a busy wave):
//   SIMD0: w0 = GRU chain        | w4 = gi0 chunk streamer (near-idle)
//   SIMD1: w1 = combine i=0 (6p) | w5 = combine i=4 (2p)
//   SIMD2: w2 = combine i=1 (5p) | w6 = fc head + out store
//   SIMD3: w3 = combine i=2 (4p) | w7 = combine i=3 (3p)
// Per-layer ns flags for l=0..4 are deferred into the next layer's body so the
// release's lgkmcnt drain hides under compute; l=5's flag stays immediate.

#define TT 16384
#define FF 2048
#define HH 16
#define LL 6
#define GG 48
#define CHUNK 64

__device__ float g_gi0p[(TT + CHUNK) * 64];

__device__ __forceinline__ float sigmoid_f(float x) { return 1.f / (1.f + __expf(-x)); }
__device__ __forceinline__ float tanh_f(float x) { return 1.f - 2.f / (__expf(2.f * x) + 1.f); }

__device__ __forceinline__ float rdlane(float v, int l) {
  union { float f; int i; } a, b;
  a.f = v; b.i = __builtin_amdgcn_readlane(a.i, l); return b.f;
}
template <int CTRL>
__device__ __forceinline__ float dppf(float v) {
  union { float f; int i; } a, b;
  a.f = v; b.i = __builtin_amdgcn_mov_dpp(a.i, CTRL, 0xF, 0xF, true); return b.f;
}
template <int Q>
__device__ __forceinline__ float qbcast(float v) { return dppf<Q | (Q << 2) | (Q << 4) | (Q << 6)>(v); }

__device__ __forceinline__ float rowsum16(float v) {
  v += dppf<0xB1>(v);   // xor1
  v += dppf<0x4E>(v);   // xor2
  v += dppf<0x141>(v);  // row_half_mirror
  v += dppf<0x140>(v);  // row_mirror
  return v;
}
__device__ __forceinline__ float dot16r(const float (&w)[16], const float (&h)[16]) {
  float s0 = w[0] * h[0], s1 = w[1] * h[1], s2 = w[2] * h[2], s3 = w[3] * h[3];
#pragma unroll
  for (int k = 4; k < 16; k += 4) {
    s0 = fmaf(w[k], h[k], s0);       s1 = fmaf(w[k + 1], h[k + 1], s1);
    s2 = fmaf(w[k + 2], h[k + 2], s2); s3 = fmaf(w[k + 3], h[k + 3], s3);
  }
  return (s0 + s1) + (s2 + s3);
}

__device__ __forceinline__ void pollGE(int* f, int target) {
  while (__hip_atomic_load(f, __ATOMIC_ACQUIRE, __HIP_MEMORY_SCOPE_WORKGROUP) < target) {}
}
__device__ __forceinline__ void sigSet(int* f, int v) {
  __hip_atomic_store(f, v, __ATOMIC_RELEASE, __HIP_MEMORY_SCOPE_WORKGROUP);
}

// ---------------- Phase 1: gi0 GEMM (permuted output) ----------------
__global__ __launch_bounds__(256) void gi0_gemm(const float* __restrict__ X,
                                                const float* __restrict__ W,
                                                const float* __restrict__ bias) {
  __shared__ float xs[64][132];
  __shared__ float ws[48][132];
  const int tid = threadIdx.x;
  const int t0 = blockIdx.x * 64;
  const int tg = tid & 15;
  const int tt = tid >> 4;
  float acc[4][3];
#pragma unroll
  for (int u = 0; u < 4; ++u)
#pragma unroll
    for (int v = 0; v < 3; ++v) acc[u][v] = 0.f;

  for (int k0 = 0; k0 < FF; k0 += 128) {
#pragma unroll
    for (int i = 0; i < 32; ++i) {
      int e = tid + 256 * i; int r = e >> 7, c = e & 127;
      xs[r][c] = X[(size_t)(t0 + r) * FF + k0 + c];
    }
#pragma unroll
    for (int i = 0; i < 24; ++i) {
      int e = tid + 256 * i; int r = e >> 7, c = e & 127;
      ws[r][c] = W[(size_t)r * FF + k0 + c];
    }
    __syncthreads();
#pragma unroll 8
    for (int c = 0; c < 128; ++c) {
      float x0 = xs[tt][c], x1 = xs[tt + 16][c], x2 = xs[tt + 32][c], x3 = xs[tt + 48][c];
      float w0 = ws[tg][c], w1 = ws[tg + 16][c], w2 = ws[tg + 32][c];
      acc[0][0] += x0 * w0; acc[0][1] += x0 * w1; acc[0][2] += x0 * w2;
      acc[1][0] += x1 * w0; acc[1][1] += x1 * w1; acc[1][2] += x1 * w2;
      acc[2][0] += x2 * w0; acc[2][1] += x2 * w1; acc[2][2] += x2 * w2;
      acc[3][0] += x3 * w0; acc[3][1] += x3 * w1; acc[3][2] += x3 * w2;
    }
    __syncthreads();
  }
#pragma unroll
  for (int u = 0; u < 4; ++u)
#pragma unroll
    for (int v = 0; v < 3; ++v)
      g_gi0p[(size_t)(t0 + tt + 16 * u) * 64 + tg * 4 + v] = acc[u][v] + bias[tg + 16 * v];
}

// ---------------- Phase 2: barrier-free sequential scan ----------------
__global__ __launch_bounds__(512, 1) void fbrnn_scan(
    const float* __restrict__ h0,
    const float* __restrict__ Whh0, const float* __restrict__ bhh0,
    const float* __restrict__ Wih, const float* __restrict__ Whh,
    const float* __restrict__ bih, const float* __restrict__ bhh,
    const float* __restrict__ Wa, const float* __restrict__ ba,
    const float* __restrict__ va,
    const float* __restrict__ fc1w, const float* __restrict__ fc1b,
    const float* __restrict__ fc2w, const float* __restrict__ fc2b,
    float* __restrict__ out) {
  __shared__ __align__(16) float nsS[2][LL * HH];     // ns, buf = t&1
  __shared__ __align__(16) float hS[2][5 * HH];       // h rows 0..4, buf = t&1
  __shared__ __align__(16) float ghS[2][5 * 64];      // gh rows 0..4, buf = t&1
  __shared__ __align__(16) float nsOut[256 * HH];     // ns5 ring for fc (w6)
  __shared__ __align__(16) float chunkS[2][CHUNK * 64];
  __shared__ int flagNs;      // chain: t*8 + l + 1 after ns_l visible
  __shared__ int cntC;        // combine waves: +1 each per step (5t+5 after step t)
  __shared__ int flagChunk;   // streamer: c+1 after chunk c staged
  __shared__ int flagOut;     // w6: t+1 after out[t] stored

  const int tid = threadIdx.x;
  const int wv = tid >> 6;
  const int lane = tid & 63;
  const int qg = lane & 3;
  const int kk = lane >> 2;
  const int k16 = lane & 15;
  const int G = (qg < 3 ? qg : 2) * 16 + kk;  // gate-major row index

  // role map: chain=w0, streamer=w4, fc=w6, combine rows {w1:0,w2:1,w3:2,w7:3,w5:4}
  const bool isChain = (wv == 0);
  const bool isStream = (wv == 4);
  const bool isFc = (wv == 6);
  const bool isComb = !isChain && !isStream && !isFc;
  const int iw = (wv == 1) ? 0 : (wv == 2) ? 1 : (wv == 3) ? 2 : (wv == 7) ? 3 : 4;

  // ---- per-role register weights ----
  float WBih[5][16], bihR[5];           // chain
  float WB5[16];  float bhh5R = 0.f;    // chain: Whh layer-5 row
  float WaR[16], WhR[16];               // combine
  float baR = 0.f, vaR = 0.f, bhhR = 0.f;
  float fc1R[16];                       // fc
  float fb1 = 0.f, fw2 = 0.f, fb2 = 0.f;

  if (isChain) {
#pragma unroll
    for (int l = 0; l < 5; ++l) {
#pragma unroll
      for (int k = 0; k < 16; ++k) WBih[l][k] = Wih[((l * GG) + G) * 16 + k];
      bihR[l] = bih[l * GG + G];
    }
#pragma unroll
    for (int k = 0; k < 16; ++k) WB5[k] = Whh[(4 * GG + G) * 16 + k];
    bhh5R = bhh[4 * GG + G];
  } else if (isComb) {
#pragma unroll
    for (int k = 0; k < 16; ++k) WaR[k] = Wa[(iw * 16 + k) * 64 + lane];
    baR = ba[iw * 64 + lane]; vaR = va[iw * 64 + lane];
    const float* wsrc = (iw == 0) ? (Whh0 + G * 16) : (Whh + ((iw - 1) * GG + G) * 16);
#pragma unroll
    for (int k = 0; k < 16; ++k) WhR[k] = wsrc[k];
    bhhR = (iw == 0) ? bhh0[G] : bhh[(iw - 1) * GG + G];
  } else if (isFc) {
    const int m = lane & 31;
#pragma unroll
    for (int k = 0; k < 16; ++k) fc1R[k] = fc1w[m * 16 + k];
    fb1 = fc1b[m]; fw2 = fc2w[m]; fb2 = fc2b[0];
  }

  if (tid == 0) { flagNs = 0; cntC = 0; flagChunk = 1; flagOut = 0; }

  float hv5 = 0.f, gh5reg = 0.f;  // chain registers
  if (isChain) {
    hv5 = h0[5 * 16 + kk];
    float hr[16];
#pragma unroll
    for (int k = 0; k < 16; ++k) hr[k] = h0[5 * 16 + k];
    gh5reg = bhh5R + dot16r(WB5, hr);
  } else if (isComb) {
    if (lane < 16) hS[1][iw * 16 + k16] = h0[iw * 16 + k16];
    float hr[16];
#pragma unroll
    for (int k = 0; k < 16; ++k) hr[k] = h0[iw * 16 + k];
    ghS[1][iw * 64 + lane] = bhhR + dot16r(WhR, hr);
  } else if (isStream) {
    const float4* src = (const float4*)g_gi0p;
    float4* dst = (float4*)(&chunkS[0][0]);
#pragma unroll
    for (int q = 0; q < 16; ++q) dst[q * 64 + lane] = src[q * 64 + lane];
  }
  __syncthreads();  // the only barrier

  // ================= streamer (w4, SIMD0 partner of the chain) =================
  if (isStream) {
#pragma unroll 1
    for (int c = 1; c < 256; ++c) {
      if (c >= 2) pollGE(&flagNs, ((c - 1) * 64 - 1) * 8 + 1);
      const float4* src = (const float4*)(g_gi0p + ((size_t)c << 12));
      float4* dst = (float4*)(&chunkS[c & 1][0]);
#pragma unroll
      for (int q = 0; q < 16; ++q) dst[q * 64 + lane] = src[q * 64 + lane];
      sigSet(&flagChunk, c + 1);
    }
    return;
  }

  // ================= fc head + output store (w6) =================
  if (isFc) {
#pragma unroll 1
    for (int t = 0; t < TT; ++t) {
      pollGE(&flagNs, t * 8 + 6);
      const float4* np = (const float4*)(nsOut + (t & 255) * 16);
      float4 a0 = np[0], a1 = np[1], a2 = np[2], a3 = np[3];
      float nr[16] = {a0.x, a0.y, a0.z, a0.w, a1.x, a1.y, a1.z, a1.w,
                      a2.x, a2.y, a2.z, a2.w, a3.x, a3.y, a3.z, a3.w};
      float y = fb1 + dot16r(fc1R, nr);
      float p = rowsum16(y * fw2);
      float o = rdlane(p, 0) + rdlane(p, 16) + fb2;
      if (lane == 0) out[t] = o;
      sigSet(&flagOut, t + 1);
    }
    return;
  }

  // ================= combine row iw (w1,w2,w3,w7,w5) =================
  if (isComb) {
#pragma unroll 1
    for (int t = 0; t < TT; ++t) {
      const int nb = t & 1;
      float pe[6], P[6], nsv[6];
#pragma unroll
      for (int j = 0; j < 6; ++j) {
        if (j >= iw) {
          pollGE(&flagNs, t * 8 + j + 1);
          const float4* np = (const float4*)(&nsS[nb][j * 16]);
          float4 a0 = np[0], a1 = np[1], a2 = np[2], a3 = np[3];
          float nr[16] = {a0.x, a0.y, a0.z, a0.w, a1.x, a1.y, a1.z, a1.w,
                          a2.x, a2.y, a2.z, a2.w, a3.x, a3.y, a3.z, a3.w};
          float u = baR + dot16r(WaR, nr);
          pe[j] = vaR * tanh_f(u);
          P[j] = dot16r(WhR, nr);
          nsv[j] = nsS[nb][j * 16 + k16];
        }
      }
      float e[6];
#pragma unroll
      for (int j = 0; j < 6; ++j) {
        if (j >= iw) {
          float r = rowsum16(pe[j]);
          e[j] = (rdlane(r, 0) + rdlane(r, 16)) + (rdlane(r, 32) + rdlane(r, 48));
        }
      }
      // softmax without max subtraction (|e| <~ 5 given 0.1-scaled weights)
      float S = 0.f, ha = 0.f, Pa = 0.f;
#pragma unroll
      for (int j = 0; j < 6; ++j) {
        if (j >= iw) {
          float w = __expf(e[j]);
          S += w; ha = fmaf(w, nsv[j], ha); Pa = fmaf(w, P[j], Pa);
        }
      }
      const float inv = 1.f / S;
      if (lane < 16) hS[nb][iw * 16 + k16] = ha * inv;
      ghS[nb][iw * 64 + lane] = bhhR + Pa * inv;
      if (lane == 0)
        __hip_atomic_fetch_add(&cntC, 1, __ATOMIC_RELEASE, __HIP_MEMORY_SCOPE_WORKGROUP);
    }
    return;
  }

  // ================= GRU chain (w0) =================
  float gnext = chunkS[0][lane];
  float ns_sg[16];
#pragma unroll 1
  for (int t = 0; t < TT; ++t) {
    const int rb = (t + 1) & 1;  // combine(t-1) output buf
    const int wb = t & 1;        // ns buf this step

    if ((t & 63) == 63) {
      const int cn = (t + 1) >> 6;
      if (cn < 256) pollGE(&flagChunk, cn + 1);
    }
    if ((t & 63) == 32) pollGE(&flagOut, t - 64);

    const float gpre = chunkS[((t + 1) >> 6) & 1][((t + 1) & 63) * 64 + lane];

    pollGE(&cntC, 5 * t);  // all 5 combine rows of step t-1 done
    float ghv[6], hv[6];
#pragma unroll
    for (int l = 0; l < 5; ++l) { ghv[l] = ghS[rb][l * 64 + lane]; hv[l] = hS[rb][l * 16 + kk]; }
    ghv[5] = gh5reg; hv[5] = hv5;

    float gi = gnext;
    float ns = 0.f;
#pragma unroll
    for (int l = 0; l < 6; ++l) {
      if (l > 0) gi = bihR[l - 1] + dot16r(WBih[l - 1], ns_sg);
      const float gh_g = ghv[l];
      const float s = gi + gh_g;
      const float sg = sigmoid_f(s);               // r at qg=0, z at qg=1
      // deferred flag for layer l-1: its release drain hides under this
      // layer's dot/sigma instead of stalling right after the ds_write.
      if (l > 0 && lane == 0) sigSet(&flagNs, t * 8 + l);
      const float sr = qbcast<0>(sg);
      const float tq = tanh_f(fmaf(sr, gh_g, gi)); // n at qg=2
      const float nn = qbcast<2>(tq);
      const float sz = qbcast<1>(sg);
      ns = fmaf(sz, hv[l] - nn, nn);
      if (qg == 0) {
        nsS[wb][l * 16 + kk] = ns;
        if (l == 5) nsOut[(t & 255) * 16 + kk] = ns;
      }
#pragma unroll
      for (int k = 0; k < 16; ++k) ns_sg[k] = rdlane(ns, 4 * k);
    }
    if (lane == 0) sigSet(&flagNs, t * 8 + 6);  // l=5 flag: latency-critical
    hv5 = ns;
    gh5reg = bhh5R + dot16r(WB5, ns_sg);
    gnext = gpre;
  }
}

extern "C" void kernel_launch(void* const* d_in, const int* in_sizes, int n_in,
                              void* d_out, int out_size, void* d_ws, size_t ws_size,
                              hipStream_t stream) {
  const float* batch = (const float*)d_in[0];
  const float* h0    = (const float*)d_in[1];
  const float* Wih0  = (const float*)d_in[2];
  const float* Whh0  = (const float*)d_in[3];
  const float* bih0  = (const float*)d_in[4];
  const float* bhh0  = (const float*)d_in[5];
  const float* Wih   = (const float*)d_in[6];
  const float* Whh   = (const float*)d_in[7];
  const float* bih   = (const float*)d_in[8];
  const float* bhh   = (const float*)d_in[9];
  const float* Wa    = (const float*)d_in[10];
  const float* ba    = (const float*)d_in[11];
  const float* va    = (const float*)d_in[12];
  const float* fc1w  = (const float*)d_in[13];
  const float* fc1b  = (const float*)d_in[14];
  const float* fc2w  = (const float*)d_in[15];
  const float* fc2b  = (const float*)d_in[16];
  float* out = (float*)d_out;
  (void)in_sizes; (void)n_in; (void)out_size; (void)d_ws; (void)ws_size;

  gi0_gemm<<<TT / 64, 256, 0, stream>>>(batch, Wih0, bih0);
  fbrnn_scan<<<1, 512, 0, stream>>>(h0, Whh0, bhh0, Wih, Whh, bih, bhh,
                                    Wa, ba, va, fc1w, fc1b, fc2w, fc2b, out);
}

// Round 8
// 30572.156 us; speedup vs baseline: 1.1314x; 1.1314x over previous
//
#include <hip/hip_runtime.h>
#include <cstdint>
#include <cstddef>

// FBRNN: T=16384, F=2048, H=16, A=64, L=6, G=3H=48.
// gi0 GEMM precomputed in permuted layout [t][k*4+gate].
// Scan: 1 block x 512 threads, zero barriers in the step loop; LDS flag sync.
// Role map (SIMD = wv%4):
//   SIMD0: w0 = GRU chain        | w4 = gi0 chunk streamer (near-idle)
//   SIMD1: w1 = combine i=0 (6r) | w5 = combine i=4 (2r)
//   SIMD2: w2 = combine i=1 (5r) | w6 = fc head + out store
//   SIMD3: w3 = combine i=2 (4r) | w7 = combine i=3 (3r)
// R8: combine fully inlines per-row reduce/exp/accumulate in the chain's
// shadow (tail = row 5 only); cached flag polls; ns5 flag released before the
// readlane broadcast; per-layer flags immediate (R7's deferral reverted).

#define TT 16384
#define FF 2048
#define HH 16
#define LL 6
#define GG 48
#define CHUNK 64

__device__ float g_gi0p[(TT + CHUNK) * 64];

__device__ __forceinline__ float sigmoid_f(float x) { return 1.f / (1.f + __expf(-x)); }
__device__ __forceinline__ float tanh_f(float x) { return 1.f - 2.f / (__expf(2.f * x) + 1.f); }

__device__ __forceinline__ float rdlane(float v, int l) {
  union { float f; int i; } a, b;
  a.f = v; b.i = __builtin_amdgcn_readlane(a.i, l); return b.f;
}
template <int CTRL>
__device__ __forceinline__ float dppf(float v) {
  union { float f; int i; } a, b;
  a.f = v; b.i = __builtin_amdgcn_mov_dpp(a.i, CTRL, 0xF, 0xF, true); return b.f;
}
template <int Q>
__device__ __forceinline__ float qbcast(float v) { return dppf<Q | (Q << 2) | (Q << 4) | (Q << 6)>(v); }

__device__ __forceinline__ float rowsum16(float v) {
  v += dppf<0xB1>(v);   // xor1
  v += dppf<0x4E>(v);   // xor2
  v += dppf<0x141>(v);  // row_half_mirror
  v += dppf<0x140>(v);  // row_mirror
  return v;
}
__device__ __forceinline__ float dot16r(const float (&w)[16], const float (&h)[16]) {
  float s0 = w[0] * h[0], s1 = w[1] * h[1], s2 = w[2] * h[2], s3 = w[3] * h[3];
#pragma unroll
  for (int k = 4; k < 16; k += 4) {
    s0 = fmaf(w[k], h[k], s0);       s1 = fmaf(w[k + 1], h[k + 1], s1);
    s2 = fmaf(w[k + 2], h[k + 2], s2); s3 = fmaf(w[k + 3], h[k + 3], s3);
  }
  return (s0 + s1) + (s2 + s3);
}

__device__ __forceinline__ void pollGE(int* f, int target) {
  while (__hip_atomic_load(f, __ATOMIC_ACQUIRE, __HIP_MEMORY_SCOPE_WORKGROUP) < target) {}
}
__device__ __forceinline__ void sigSet(int* f, int v) {
  __hip_atomic_store(f, v, __ATOMIC_RELEASE, __HIP_MEMORY_SCOPE_WORKGROUP);
}

// ---------------- Phase 1: gi0 GEMM (permuted output) ----------------
__global__ __launch_bounds__(256) void gi0_gemm(const float* __restrict__ X,
                                                const float* __restrict__ W,
                                                const float* __restrict__ bias) {
  __shared__ float xs[64][132];
  __shared__ float ws[48][132];
  const int tid = threadIdx.x;
  const int t0 = blockIdx.x * 64;
  const int tg = tid & 15;
  const int tt = tid >> 4;
  float acc[4][3];
#pragma unroll
  for (int u = 0; u < 4; ++u)
#pragma unroll
    for (int v = 0; v < 3; ++v) acc[u][v] = 0.f;

  for (int k0 = 0; k0 < FF; k0 += 128) {
#pragma unroll
    for (int i = 0; i < 32; ++i) {
      int e = tid + 256 * i; int r = e >> 7, c = e & 127;
      xs[r][c] = X[(size_t)(t0 + r) * FF + k0 + c];
    }
#pragma unroll
    for (int i = 0; i < 24; ++i) {
      int e = tid + 256 * i; int r = e >> 7, c = e & 127;
      ws[r][c] = W[(size_t)r * FF + k0 + c];
    }
    __syncthreads();
#pragma unroll 8
    for (int c = 0; c < 128; ++c) {
      float x0 = xs[tt][c], x1 = xs[tt + 16][c], x2 = xs[tt + 32][c], x3 = xs[tt + 48][c];
      float w0 = ws[tg][c], w1 = ws[tg + 16][c], w2 = ws[tg + 32][c];
      acc[0][0] += x0 * w0; acc[0][1] += x0 * w1; acc[0][2] += x0 * w2;
      acc[1][0] += x1 * w0; acc[1][1] += x1 * w1; acc[1][2] += x1 * w2;
      acc[2][0] += x2 * w0; acc[2][1] += x2 * w1; acc[2][2] += x2 * w2;
      acc[3][0] += x3 * w0; acc[3][1] += x3 * w1; acc[3][2] += x3 * w2;
    }
    __syncthreads();
  }
#pragma unroll
  for (int u = 0; u < 4; ++u)
#pragma unroll
    for (int v = 0; v < 3; ++v)
      g_gi0p[(size_t)(t0 + tt + 16 * u) * 64 + tg * 4 + v] = acc[u][v] + bias[tg + 16 * v];
}

// ---------------- Phase 2: barrier-free sequential scan ----------------
__global__ __launch_bounds__(512, 1) void fbrnn_scan(
    const float* __restrict__ h0,
    const float* __restrict__ Whh0, const float* __restrict__ bhh0,
    const float* __restrict__ Wih, const float* __restrict__ Whh,
    const float* __restrict__ bih, const float* __restrict__ bhh,
    const float* __restrict__ Wa, const float* __restrict__ ba,
    const float* __restrict__ va,
    const float* __restrict__ fc1w, const float* __restrict__ fc1b,
    const float* __restrict__ fc2w, const float* __restrict__ fc2b,
    float* __restrict__ out) {
  __shared__ __align__(16) float nsS[2][LL * HH];     // ns, buf = t&1
  __shared__ __align__(16) float hS[2][5 * HH];       // h rows 0..4, buf = t&1
  __shared__ __align__(16) float ghS[2][5 * 64];      // gh rows 0..4, buf = t&1
  __shared__ __align__(16) float nsOut[256 * HH];     // ns5 ring for fc (w6)
  __shared__ __align__(16) float chunkS[2][CHUNK * 64];
  __shared__ int flagNs;      // chain: t*8 + l + 1 after ns_l visible
  __shared__ int cntC;        // combine waves: +1 each per step (5t+5 after step t)
  __shared__ int flagChunk;   // streamer: c+1 after chunk c staged
  __shared__ int flagOut;     // w6: t+1 after out[t] stored

  const int tid = threadIdx.x;
  const int wv = tid >> 6;
  const int lane = tid & 63;
  const int qg = lane & 3;
  const int kk = lane >> 2;
  const int k16 = lane & 15;
  const int G = (qg < 3 ? qg : 2) * 16 + kk;  // gate-major row index

  // role map: chain=w0, streamer=w4, fc=w6, combine rows {w1:0,w2:1,w3:2,w7:3,w5:4}
  const bool isChain = (wv == 0);
  const bool isStream = (wv == 4);
  const bool isFc = (wv == 6);
  const bool isComb = !isChain && !isStream && !isFc;
  const int iw = (wv == 1) ? 0 : (wv == 2) ? 1 : (wv == 3) ? 2 : (wv == 7) ? 3 : 4;

  // ---- per-role register weights ----
  float WBih[5][16], bihR[5];           // chain
  float WB5[16];  float bhh5R = 0.f;    // chain: Whh layer-5 row
  float WaR[16], WhR[16];               // combine
  float baR = 0.f, vaR = 0.f, bhhR = 0.f;
  float fc1R[16];                       // fc
  float fb1 = 0.f, fw2 = 0.f, fb2 = 0.f;

  if (isChain) {
#pragma unroll
    for (int l = 0; l < 5; ++l) {
#pragma unroll
      for (int k = 0; k < 16; ++k) WBih[l][k] = Wih[((l * GG) + G) * 16 + k];
      bihR[l] = bih[l * GG + G];
    }
#pragma unroll
    for (int k = 0; k < 16; ++k) WB5[k] = Whh[(4 * GG + G) * 16 + k];
    bhh5R = bhh[4 * GG + G];
  } else if (isComb) {
#pragma unroll
    for (int k = 0; k < 16; ++k) WaR[k] = Wa[(iw * 16 + k) * 64 + lane];
    baR = ba[iw * 64 + lane]; vaR = va[iw * 64 + lane];
    const float* wsrc = (iw == 0) ? (Whh0 + G * 16) : (Whh + ((iw - 1) * GG + G) * 16);
#pragma unroll
    for (int k = 0; k < 16; ++k) WhR[k] = wsrc[k];
    bhhR = (iw == 0) ? bhh0[G] : bhh[(iw - 1) * GG + G];
  } else if (isFc) {
    const int m = lane & 31;
#pragma unroll
    for (int k = 0; k < 16; ++k) fc1R[k] = fc1w[m * 16 + k];
    fb1 = fc1b[m]; fw2 = fc2w[m]; fb2 = fc2b[0];
  }

  if (tid == 0) { flagNs = 0; cntC = 0; flagChunk = 1; flagOut = 0; }

  float hv5 = 0.f, gh5reg = 0.f;  // chain registers
  if (isChain) {
    hv5 = h0[5 * 16 + kk];
    float hr[16];
#pragma unroll
    for (int k = 0; k < 16; ++k) hr[k] = h0[5 * 16 + k];
    gh5reg = bhh5R + dot16r(WB5, hr);
  } else if (isComb) {
    if (lane < 16) hS[1][iw * 16 + k16] = h0[iw * 16 + k16];
    float hr[16];
#pragma unroll
    for (int k = 0; k < 16; ++k) hr[k] = h0[iw * 16 + k];
    ghS[1][iw * 64 + lane] = bhhR + dot16r(WhR, hr);
  } else if (isStream) {
    const float4* src = (const float4*)g_gi0p;
    float4* dst = (float4*)(&chunkS[0][0]);
#pragma unroll
    for (int q = 0; q < 16; ++q) dst[q * 64 + lane] = src[q * 64 + lane];
  }
  __syncthreads();  // the only barrier

  // ================= streamer (w4, SIMD0 partner of the chain) =================
  if (isStream) {
#pragma unroll 1
    for (int c = 1; c < 256; ++c) {
      if (c >= 2) pollGE(&flagNs, ((c - 1) * 64 - 1) * 8 + 1);
      const float4* src = (const float4*)(g_gi0p + ((size_t)c << 12));
      float4* dst = (float4*)(&chunkS[c & 1][0]);
#pragma unroll
      for (int q = 0; q < 16; ++q) dst[q * 64 + lane] = src[q * 64 + lane];
      sigSet(&flagChunk, c + 1);
    }
    return;
  }

  // ================= fc head + output store (w6) =================
  if (isFc) {
#pragma unroll 1
    for (int t = 0; t < TT; ++t) {
      pollGE(&flagNs, t * 8 + 6);
      const float4* np = (const float4*)(nsOut + (t & 255) * 16);
      float4 a0 = np[0], a1 = np[1], a2 = np[2], a3 = np[3];
      float nr[16] = {a0.x, a0.y, a0.z, a0.w, a1.x, a1.y, a1.z, a1.w,
                      a2.x, a2.y, a2.z, a2.w, a3.x, a3.y, a3.z, a3.w};
      float y = fb1 + dot16r(fc1R, nr);
      float p = rowsum16(y * fw2);
      float o = rdlane(p, 0) + rdlane(p, 16) + fb2;
      if (lane == 0) out[t] = o;
      sigSet(&flagOut, t + 1);
    }
    return;
  }

  // ================= combine row iw (w1,w2,w3,w7,w5) =================
  if (isComb) {
    int fcache = 0;  // flagNs is monotonic: cache it across polls
#pragma unroll 1
    for (int t = 0; t < TT; ++t) {
      const int nb = t & 1;
      float S = 0.f, ha = 0.f, Pa = 0.f;
      // rows iw..5: fully processed inline; rows <5 sit in the chain's shadow,
      // so only row 5's block is on the critical path.
#pragma unroll
      for (int j = 0; j < 6; ++j) {
        if (j >= iw) {
          const int need = t * 8 + j + 1;
          if (fcache < need) {
            do {
              fcache = __hip_atomic_load(&flagNs, __ATOMIC_ACQUIRE, __HIP_MEMORY_SCOPE_WORKGROUP);
            } while (fcache < need);
          }
          const float4* np = (const float4*)(&nsS[nb][j * 16]);
          float4 a0 = np[0], a1 = np[1], a2 = np[2], a3 = np[3];
          float nr[16] = {a0.x, a0.y, a0.z, a0.w, a1.x, a1.y, a1.z, a1.w,
                          a2.x, a2.y, a2.z, a2.w, a3.x, a3.y, a3.z, a3.w};
          const float nsv = nsS[nb][j * 16 + k16];
          float u = baR + dot16r(WaR, nr);
          float pe = vaR * tanh_f(u);
          float P = dot16r(WhR, nr);
          float r = rowsum16(pe);
          float e = (rdlane(r, 0) + rdlane(r, 16)) + (rdlane(r, 32) + rdlane(r, 48));
          // softmax without max subtraction (|e| <~ 5 given 0.1-scaled weights)
          float w = __expf(e);
          S += w; ha = fmaf(w, nsv, ha); Pa = fmaf(w, P, Pa);
        }
      }
      const float inv = 1.f / S;
      if (lane < 16) hS[nb][iw * 16 + k16] = ha * inv;
      ghS[nb][iw * 64 + lane] = bhhR + Pa * inv;
      if (lane == 0)
        __hip_atomic_fetch_add(&cntC, 1, __ATOMIC_RELEASE, __HIP_MEMORY_SCOPE_WORKGROUP);
    }
    return;
  }

  // ================= GRU chain (w0) =================
  float gnext = chunkS[0][lane];
  float ns_sg[16];
#pragma unroll 1
  for (int t = 0; t < TT; ++t) {
    const int rb = (t + 1) & 1;  // combine(t-1) output buf
    const int wb = t & 1;        // ns buf this step

    if ((t & 63) == 63) {
      const int cn = (t + 1) >> 6;
      if (cn < 256) pollGE(&flagChunk, cn + 1);
    }
    if ((t & 63) == 32) pollGE(&flagOut, t - 64);

    const float gpre = chunkS[((t + 1) >> 6) & 1][((t + 1) & 63) * 64 + lane];

    pollGE(&cntC, 5 * t);  // all 5 combine rows of step t-1 done
    float ghv[6], hv[6];
#pragma unroll
    for (int l = 0; l < 5; ++l) { ghv[l] = ghS[rb][l * 64 + lane]; hv[l] = hS[rb][l * 16 + kk]; }
    ghv[5] = gh5reg; hv[5] = hv5;

    float gi = gnext;
    float ns = 0.f;
#pragma unroll
    for (int l = 0; l < 6; ++l) {
      if (l > 0) gi = bihR[l - 1] + dot16r(WBih[l - 1], ns_sg);
      const float gh_g = ghv[l];
      const float s = gi + gh_g;
      const float sg = sigmoid_f(s);               // r at qg=0, z at qg=1
      const float sr = qbcast<0>(sg);
      const float tq = tanh_f(fmaf(sr, gh_g, gi)); // n at qg=2
      const float nn = qbcast<2>(tq);
      const float sz = qbcast<1>(sg);
      ns = fmaf(sz, hv[l] - nn, nn);
      if (qg == 0) {
        nsS[wb][l * 16 + kk] = ns;
        if (l == 5) nsOut[(t & 255) * 16 + kk] = ns;
      }
      // l=5's flag is latency-critical for the combine tails: release it
      // BEFORE the readlane broadcast (chain's post-release work has slack).
      if (l == 5 && lane == 0) sigSet(&flagNs, t * 8 + 6);
#pragma unroll
      for (int k = 0; k < 16; ++k) ns_sg[k] = rdlane(ns, 4 * k);
      if (l < 5 && lane == 0) sigSet(&flagNs, t * 8 + l + 1);
    }
    hv5 = ns;
    gh5reg = bhh5R + dot16r(WB5, ns_sg);
    gnext = gpre;
  }
}

extern "C" void kernel_launch(void* const* d_in, const int* in_sizes, int n_in,
                              void* d_out, int out_size, void* d_ws, size_t ws_size,
                              hipStream_t stream) {
  const float* batch = (const float*)d_in[0];
  const float* h0    = (const float*)d_in[1];
  const float* Wih0  = (const float*)d_in[2];
  const float* Whh0  = (const float*)d_in[3];
  const float* bih0  = (const float*)d_in[4];
  const float* bhh0  = (const float*)d_in[5];
  const float* Wih   = (const float*)d_in[6];
  const float* Whh   = (const float*)d_in[7];
  const float* bih   = (const float*)d_in[8];
  const float* bhh   = (const float*)d_in[9];
  const float* Wa    = (const float*)d_in[10];
  const float* ba    = (const float*)d_in[11];
  const float* va    = (const float*)d_in[12];
  const float* fc1w  = (const float*)d_in[13];
  const float* fc1b  = (const float*)d_in[14];
  const float* fc2w  = (const float*)d_in[15];
  const float* fc2b  = (const float*)d_in[16];
  float* out = (float*)d_out;
  (void)in_sizes; (void)n_in; (void)out_size; (void)d_ws; (void)ws_size;

  gi0_gemm<<<TT / 64, 256, 0, stream>>>(batch, Wih0, bih0);
  fbrnn_scan<<<1, 512, 0, stream>>>(h0, Whh0, bhh0, Wih, Whh, bih, bhh,
                                    Wa, ba, va, fc1w, fc1b, fc2w, fc2b, out);
}